// Round 2
// baseline (854.888 us; speedup 1.0000x reference)
//
#include <hip/hip_runtime.h>

// ALiBi bias subtraction:
//   out[b,h,i,j] = scores[b,h,i,j] - slope(h) * (pos[b,i] - pos[b,j])
//   slope(h) = 2^(-8*(h+1)/H) = exp2(-0.5*(h+1)) for H=16
//   pos[b,j] = positions[token_indices[b,j]]
// Memory-bound: 512 MiB in + 512 MiB out; floor ~170 us at 6.3 TB/s.

constexpr int B_   = 2;
constexpr int H_   = 16;
constexpr int S_   = 2048;

// Step 1: gather positions via token_indices -> posg[b*S + j]
// (tiny: B*S = 4096 elements; removes dependent double-gather from hot loop)
__global__ void alibi_gather_pos(const float* __restrict__ positions,
                                 const int* __restrict__ token_indices,
                                 float* __restrict__ posg, int n) {
    int t = blockIdx.x * blockDim.x + threadIdx.x;
    if (t < n) {
        posg[t] = positions[token_indices[t]];
    }
}

// Step 2: streaming elementwise kernel, float4 vectorized (16 B/lane).
__global__ __launch_bounds__(256) void alibi_apply(
    const float4* __restrict__ scores4,
    const float* __restrict__ posg,
    float4* __restrict__ out4,
    long n4) {
    const long stride = (long)gridDim.x * blockDim.x;
    for (long idx = (long)blockIdx.x * blockDim.x + threadIdx.x; idx < n4;
         idx += stride) {
        // idx indexes float4 elements. Layout: [B][H][S][S/4]
        const int  j4  = (int)(idx & (S_ / 4 - 1));      // column quad
        const long row = idx >> 9;                        // / (S/4 = 512)
        const int  i   = (int)(row & (S_ - 1));           // row within [S]
        const long bh  = row >> 11;                       // / S
        const int  h   = (int)(bh & (H_ - 1));
        const int  b   = (int)(bh >> 4);                  // / H

        const float slope = exp2f(-0.5f * (float)(h + 1));  // 1x v_exp_f32
        const float pi    = posg[b * S_ + i];               // L1-resident
        const float4 pj   = *reinterpret_cast<const float4*>(&posg[b * S_ + j4 * 4]);

        const float4 s = scores4[idx];
        float4 o;
        o.x = s.x - slope * (pi - pj.x);
        o.y = s.y - slope * (pi - pj.y);
        o.z = s.z - slope * (pi - pj.z);
        o.w = s.w - slope * (pi - pj.w);
        out4[idx] = o;
    }
}

extern "C" void kernel_launch(void* const* d_in, const int* in_sizes, int n_in,
                              void* d_out, int out_size, void* d_ws, size_t ws_size,
                              hipStream_t stream) {
    const float* scores        = (const float*)d_in[0];  // [B,H,S,S] f32
    const float* positions     = (const float*)d_in[1];  // [CTX] f32
    const int*   token_indices = (const int*)d_in[2];    // [B,S] int

    float* out  = (float*)d_out;
    float* posg = (float*)d_ws;  // B*S floats = 16 KB scratch

    const int npos = B_ * S_;
    alibi_gather_pos<<<(npos + 255) / 256, 256, 0, stream>>>(positions,
                                                             token_indices,
                                                             posg, npos);

    const long n4 = (long)B_ * H_ * S_ * (S_ / 4);
    const int  blocks = 2048;  // 256 CUs x 8 blocks/CU; grid-stride the rest
    alibi_apply<<<blocks, 256, 0, stream>>>(
        reinterpret_cast<const float4*>(scores), posg,
        reinterpret_cast<float4*>(out), n4);
}

// Round 6
// 834.622 us; speedup vs baseline: 1.0243x; 1.0243x over previous
//
#include <hip/hip_runtime.h>

// ALiBi bias subtraction:
//   out[b,h,i,j] = scores[b,h,i,j] - slope(h) * (pos[b,i] - pos[b,j])
//   slope(h) = exp2(-8*(h+1)/H) = exp2(-0.5*(h+1)) for H=16
//   pos[b,j] = positions[token_indices[b,j]]
// Memory-bound: 512 MiB read + 512 MiB write; floor ~170 us at 6.3 TB/s.

constexpr int B_  = 2;
constexpr int H_  = 16;
constexpr int S_  = 2048;
constexpr int SQ_ = S_ / 4;               // 512 float4 per row
constexpr int ROWS_PER_BLOCK = 32;
constexpr int BLOCKS_PER_BH  = S_ / ROWS_PER_BLOCK;  // 64

typedef float f32x4 __attribute__((ext_vector_type(4)));

// Step 1: gather positions via token_indices -> posg[b*S + j]  (4096 elems)
__global__ void alibi_gather_pos(const float* __restrict__ positions,
                                 const int* __restrict__ token_indices,
                                 float* __restrict__ posg, int n) {
    int t = blockIdx.x * blockDim.x + threadIdx.x;
    if (t < n) {
        posg[t] = positions[token_indices[t]];
    }
}

// Step 2: slab-mapped streaming kernel.
// Block = one (b,h) x 32-row slab: slope computed once, pj held in registers
// across all 32 rows; scores/out accessed as contiguous 256 KB per block.
__global__ __launch_bounds__(256) void alibi_apply(
    const f32x4* __restrict__ scores4,
    const float* __restrict__ posg,
    f32x4* __restrict__ out4) {
    const int bid  = blockIdx.x;
    const int bh   = bid >> 6;            // / BLOCKS_PER_BH
    const int slab = bid & (BLOCKS_PER_BH - 1);
    const int h    = bh & (H_ - 1);
    const int b    = bh >> 4;

    const float slope = exp2f(-0.5f * (float)(h + 1));  // once per block
    const float* __restrict__ pb = posg + b * S_;
    const int i0 = slab * ROWS_PER_BLOCK;

    // Column-position quads for this thread: loaded ONCE, reused for 32 rows.
    const int j4a = threadIdx.x;          // quad 0..255
    const int j4b = threadIdx.x + 256;    // quad 256..511
    const f32x4 pja = *reinterpret_cast<const f32x4*>(pb + 4 * j4a);
    const f32x4 pjb = *reinterpret_cast<const f32x4*>(pb + 4 * j4b);

    // Base float4-offset of (b,h,i0,0); max 33.5M so int is safe.
    const int base = (bh * S_ + i0) * SQ_;

    #pragma unroll 4
    for (int r = 0; r < ROWS_PER_BLOCK; ++r) {
        const float pi = pb[i0 + r];      // wave-uniform, L1-resident
        const int   rb = base + r * SQ_;

        f32x4 s0 = __builtin_nontemporal_load(scores4 + rb + j4a);
        f32x4 s1 = __builtin_nontemporal_load(scores4 + rb + j4b);

        f32x4 o0, o1;
        o0.x = s0.x - slope * (pi - pja.x);
        o0.y = s0.y - slope * (pi - pja.y);
        o0.z = s0.z - slope * (pi - pja.z);
        o0.w = s0.w - slope * (pi - pja.w);
        o1.x = s1.x - slope * (pi - pjb.x);
        o1.y = s1.y - slope * (pi - pjb.y);
        o1.z = s1.z - slope * (pi - pjb.z);
        o1.w = s1.w - slope * (pi - pjb.w);

        __builtin_nontemporal_store(o0, out4 + rb + j4a);
        __builtin_nontemporal_store(o1, out4 + rb + j4b);
    }
}

extern "C" void kernel_launch(void* const* d_in, const int* in_sizes, int n_in,
                              void* d_out, int out_size, void* d_ws, size_t ws_size,
                              hipStream_t stream) {
    const float* scores        = (const float*)d_in[0];  // [B,H,S,S] f32
    const float* positions     = (const float*)d_in[1];  // [CTX] f32
    const int*   token_indices = (const int*)d_in[2];    // [B,S] int

    float* out  = (float*)d_out;
    float* posg = (float*)d_ws;  // B*S floats = 16 KB scratch

    const int npos = B_ * S_;
    alibi_gather_pos<<<(npos + 255) / 256, 256, 0, stream>>>(positions,
                                                             token_indices,
                                                             posg, npos);

    const int blocks = B_ * H_ * BLOCKS_PER_BH;  // 2048 = 8 blocks/CU
    alibi_apply<<<blocks, 256, 0, stream>>>(
        reinterpret_cast<const f32x4*>(scores), posg,
        reinterpret_cast<f32x4*>(out));
}